// Round 10
// baseline (1021.299 us; speedup 1.0000x reference)
//
#include <hip/hip_runtime.h>

#define T_STEPS 32
#define BATCH   16
#define NBPB    8
#define NBLK    (BATCH * NBPB)     // 128
#define NTHR    1024
#define LSL     512                // l-slots per block
#define MSTR    68                 // 16B-aligned rows; b128 banking == stride-1 (free)
#define CO      332

// comm floats (zeroed by hipMemsetAsync). All cross-block slots are per-(b,t)
// write-once; S/P slots are strictly positive -> 0 is a "not ready" sentinel.
#define OFF_SLS   0                                        // [b][t][g][2] S partials (flags)
#define OFF_SLP   (OFF_SLS + BATCH*T_STEPS*16)             // [b][t][g][2] P partials (flags)
#define OFF_RSUM  (OFF_SLP + BATCH*T_STEPS*16)             // [b][t][64] r~ sums
#define OFF_HE    (OFF_RSUM + BATCH*T_STEPS*64)            // [b][t][g][4] er halos
#define OFF_HWB   (OFF_HE + BATCH*T_STEPS*NBPB*4)          // [b][0..32][g][4] wb halos (unnorm)
#define COMM_FLOATS (OFF_HWB + BATCH*(T_STEPS+1)*NBPB*4)

__device__ __forceinline__ float waveSum(float v) {
#pragma unroll
  for (int off = 32; off > 0; off >>= 1) v += __shfl_xor(v, off, 64);
  return v;
}
__device__ __forceinline__ float sigmoidf(float x) { return 1.f / (1.f + __expf(-x)); }
__device__ __forceinline__ float softplusf(float x) { return x > 15.f ? x : log1pf(__expf(x)); }
__device__ __forceinline__ float aload(const float* p) {
  return __hip_atomic_load(p, __ATOMIC_RELAXED, __HIP_MEMORY_SCOPE_AGENT);
}
__device__ __forceinline__ void astore(float* p, float v) {
  __hip_atomic_store(p, v, __ATOMIC_RELAXED, __HIP_MEMORY_SCOPE_AGENT);
}
__device__ __forceinline__ void astoreRel(float* p, float v) {
  __hip_atomic_store(p, v, __ATOMIC_RELEASE, __HIP_MEMORY_SCOPE_AGENT);
}

// Per-wave spin on a 16-word slot array (8 blocks x {A,B}); returns sums.
// Only lanes 0..15 touch the fabric -> 16 loads/iteration/wave.
__device__ __forceinline__ void spin2(const float* slot, int lane, float& sA, float& sB) {
  unsigned u;
  for (;;) {
    u = (lane < 16)
        ? __hip_atomic_load((const unsigned*)slot + lane, __ATOMIC_RELAXED,
                            __HIP_MEMORY_SCOPE_AGENT)
        : 1u;
    unsigned long long m = __ballot(u != 0);
    if ((m & 0xffffULL) == 0xffffULL) break;
    __builtin_amdgcn_s_sleep(1);
  }
  float f = (lane < 16) ? __uint_as_float(u) : 0.f;
  sA = waveSum(((lane & 1) == 0) ? f : 0.f);
  sB = waveSum(((lane & 1) == 1) ? f : 0.f);
}

__global__ void __launch_bounds__(NTHR, 1) ntm_kernel(
    const float* __restrict__ inp, const float* __restrict__ Wc,
    const float* __restrict__ bcv, float* __restrict__ dout,
    float* __restrict__ comm)
{
  const int blkid = blockIdx.x;
  const int b   = blkid & 15;     // blkid%8 == b%8 -> per-batch XCD co-location
  const int g   = blkid >> 4;
  const int tid = threadIdx.x;
  const int wv  = tid >> 6;
  const int lane = tid & 63;

  __shared__ float mem[LSL * MSTR];                 // 136 KB block-private
  __shared__ float wpR[LSL], wpW[LSL];              // normalized prev weights
  __shared__ float wbR[LSL], wbW[LSL];              // sharpened, unnormalized
  __shared__ float erR[LSL], erW[LSL];              // softmax numerators
  __shared__ __align__(16) float kr[64], kw[64];
  __shared__ __align__(16) float eldsA[2][64], aldsA[2][64];
  __shared__ float paccT[CO], outP[64], rstage[64], psc[12];
  __shared__ float scrA[16], scrB[16], scrC[8], scrD[8];
  __shared__ float scrR[16][64];

  // ---------------- prologue (no cross-block sync) ----------------
  for (int i = tid; i < LSL * MSTR; i += NTHR) mem[i] = 0.f;
  if (tid < LSL) { wpR[tid] = 0.f; wpW[tid] = 0.f; }
  if (g == 0 && tid == 0) { wpR[0] = 1.f; wpW[0] = 1.f; }
  if (tid < 64) outP[tid] = 0.f;
  if (tid < CO) {            // pacc(0) = bc + Wx*x(0); out(-1)=0, r(-1)=0
    float acc = bcv[tid];
    const float* x0 = inp + b * 64;
    const float* wc = Wc + tid;
#pragma unroll 8
    for (int i = 0; i < 64; ++i) acc = fmaf(x0[i], wc[(size_t)i * CO], acc);
    paccT[tid] = acc;
  }
  {
    float* h0 = comm + OFF_HWB + ((size_t)(b * (T_STEPS + 1)) * NBPB + g) * 4;
    if (tid == 0) { float v = (g == 0) ? 1.f : 0.f; astore(h0 + 0, v); astore(h0 + 2, v); }
    if (tid == 1) { astore(h0 + 1, 0.f); astore(h0 + 3, 0.f); }
  }
  float invPRp = 1.f, invPWp = 1.f;   // invP(t-1); slot-0 halos are pre-normalized
  __syncthreads();

  for (int t = 0; t < T_STEPS; ++t) {
    float* slS = comm + OFF_SLS + (size_t)(b * T_STEPS + t) * 16;
    float* slP = comm + OFF_SLP + (size_t)(b * T_STEPS + t) * 16;
    float* rS  = comm + OFF_RSUM + (size_t)(b * T_STEPS + t) * 64;
    float* hE  = comm + OFF_HE + ((size_t)(b * T_STEPS + t) * NBPB + g) * 4;
    float* hWBt = comm + OFF_HWB + ((size_t)(b * (T_STEPS + 1) + t) * NBPB) * 4;
    float* hWBn = comm + OFF_HWB + ((size_t)(b * (T_STEPS + 1) + t + 1) * NBPB + g) * 4;

    // ---------- P0: GEMM(t) = paccT + Wr*r(t-1) ----------
    if (tid < 2 * CO) {
      const int col = tid >> 1, h = tid & 1;
      float part = h ? 0.f : paccT[col];
      if (t > 0) {
        const float* wc = Wc + (size_t)(128 + 32 * h) * CO + col;
#pragma unroll 8
        for (int j = 0; j < 32; ++j)
          part = fmaf(rstage[32 * h + j], wc[(size_t)j * CO], part);
      }
      float acc = part + __shfl_xor(part, 1, 64);
      if (h == 0) {
        if (col < 64) { outP[col] = acc; if (g == 0) dout[((size_t)t * BATCH + b) * 64 + col] = acc; }
        else if (col < 128) kr[col - 64] = acc;
        else if (col < 134) psc[col - 128] = acc;          // beta_r,g_r,ga_r,s_r0..2
        else if (col < 198) kw[col - 134] = acc;
        else if (col < 204) psc[6 + col - 198] = acc;      // beta_w,g_w,ga_w,s_w0..2
        else if (col < 268) eldsA[t & 1][col - 204] = sigmoidf(acc);
        else                aldsA[t & 1][col - 268] = acc;
      }
    }
    __syncthreads();   // S1

    // per-wave norms + betas (registers, no sync)
    float invnkR, invnkW, betaR, betaW;
    {
      float v = kr[lane]; invnkR = 1.f / sqrtf(waveSum(v * v) + 1e-14f);
      float u = kw[lane]; invnkW = 1.f / sqrtf(waveSum(u * u) + 1e-14f);
      betaR = softplusf(psc[0]); betaW = softplusf(psc[6]);
    }

    // ---------- P1: fused lazy-update(t-1) + content (b128) ----------
    {
      const int l = tid >> 1, h = tid & 1;
      float4* mrow4 = (float4*)&mem[l * MSTR + 32 * h];
      const float4* k4 = (const float4*)kr + 8 * h;
      const float4* w4 = (const float4*)kw + 8 * h;
      float ss = 0.f, dr = 0.f, dw = 0.f;
      if (t > 0) {
        const float wWl = wpW[l];
        const float4* e4 = (const float4*)eldsA[(t + 1) & 1] + 8 * h;
        const float4* a4 = (const float4*)aldsA[(t + 1) & 1] + 8 * h;
#pragma unroll
        for (int q = 0; q < 8; ++q) {
          float4 v = mrow4[q];
          float4 e = e4[q], a = a4[q], kk = k4[q], ww = w4[q];
          v.x = fmaf(wWl, a.x, fmaf(v.x, -(wWl * e.x), v.x));
          v.y = fmaf(wWl, a.y, fmaf(v.y, -(wWl * e.y), v.y));
          v.z = fmaf(wWl, a.z, fmaf(v.z, -(wWl * e.z), v.z));
          v.w = fmaf(wWl, a.w, fmaf(v.w, -(wWl * e.w), v.w));
          mrow4[q] = v;
          ss = fmaf(v.x, v.x, fmaf(v.y, v.y, fmaf(v.z, v.z, fmaf(v.w, v.w, ss))));
          dr = fmaf(v.x, kk.x, fmaf(v.y, kk.y, fmaf(v.z, kk.z, fmaf(v.w, kk.w, dr))));
          dw = fmaf(v.x, ww.x, fmaf(v.y, ww.y, fmaf(v.z, ww.z, fmaf(v.w, ww.w, dw))));
        }
      }
      ss += __shfl_xor(ss, 1, 64);
      dr += __shfl_xor(dr, 1, 64);
      dw += __shfl_xor(dw, 1, 64);
      float rinv = rsqrtf(ss + 1e-14f);
      float eRv = __expf(betaR * (dr * rinv * invnkR - 1.f));   // stable: K<=1
      float eWv = __expf(betaW * (dw * rinv * invnkW - 1.f));
      if (h == 0) {
        erR[l] = eRv; erW[l] = eWv;
        if (l == 0)       { astore(hE + 0, eRv); astore(hE + 2, eWv); }
        if (l == LSL - 1) { astore(hE + 1, eRv); astore(hE + 3, eWv); }
      }
      float sRl = h ? 0.f : eRv, sWl = h ? 0.f : eWv;
      sRl = waveSum(sRl); sWl = waveSum(sWl);
      if (!lane) { scrA[wv] = sRl; scrB[wv] = sWl; }
    }
    __syncthreads();   // S2 (drains halo stores per-wave before flag release)
    if (tid == 0) {
      float a = 0.f, bb = 0.f;
#pragma unroll
      for (int j = 0; j < 16; ++j) { a += scrA[j]; bb += scrB[j]; }
      astoreRel(slS + 2 * g + 0, a);
      astoreRel(slS + 2 * g + 1, bb);
    }

    // ---------- P2a: sharpen (waves 0-7, spin on S) || prefetch (waves 8+) ----------
    if (tid < LSL) {
      float sR_, sW_; spin2(slS, lane, sR_, sW_);
      const float invSR = 1.f / sR_, invSW = 1.f / sW_;
      float gR = sigmoidf(psc[1]), gaR = softplusf(psc[2]) + 1.f;
      float x0 = psc[3], x1 = psc[4], x2 = psc[5];
      float mx = fmaxf(x0, fmaxf(x1, x2));
      float e0 = __expf(x0 - mx), e1 = __expf(x1 - mx), e2 = __expf(x2 - mx);
      float es = 1.f / (e0 + e1 + e2);
      float sr0 = e0 * es, sr1 = e1 * es, sr2 = e2 * es;
      float gW = sigmoidf(psc[7]), gaW = softplusf(psc[8]) + 1.f;
      float y0 = psc[9], y1 = psc[10], y2 = psc[11];
      float my = fmaxf(y0, fmaxf(y1, y2));
      float f0 = __expf(y0 - my), f1 = __expf(y1 - my), f2 = __expf(y2 - my);
      float fs = 1.f / (f0 + f1 + f2);
      float sw0 = f0 * fs, sw1 = f1 * fs, sw2 = f2 * fs;
      const float aR = gR * invSR, bR = 1.f - gR;
      const float aW = gW * invSW, bW = 1.f - gW;

      float erm, ewm, prm, pwm, erp, ewp, prp, pwp;
      if (tid == 0) {
        const int gm = (g + 7) & 7;
        const float* hEm = comm + OFF_HE + ((size_t)(b * T_STEPS + t) * NBPB + gm) * 4;
        const float* hWm = hWBt + gm * 4;
        erm = aload(hEm + 1); ewm = aload(hEm + 3);
        prm = aload(hWm + 1) * invPRp; pwm = aload(hWm + 3) * invPWp;
      } else { erm = erR[tid - 1]; ewm = erW[tid - 1]; prm = wpR[tid - 1]; pwm = wpW[tid - 1]; }
      if (tid == LSL - 1) {
        const int gp = (g + 1) & 7;
        const float* hEp = comm + OFF_HE + ((size_t)(b * T_STEPS + t) * NBPB + gp) * 4;
        const float* hWp = hWBt + gp * 4;
        erp = aload(hEp + 0); ewp = aload(hEp + 2);
        prp = aload(hWp + 0) * invPRp; pwp = aload(hWp + 2) * invPWp;
      } else { erp = erR[tid + 1]; ewp = erW[tid + 1]; prp = wpR[tid + 1]; pwp = wpW[tid + 1]; }

      float wgm = aR * erm + bR * prm;
      float wg0 = aR * erR[tid] + bR * wpR[tid];
      float wgp = aR * erp + bR * prp;
      float wR = __powf(sr0 * wgm + sr1 * wg0 + sr2 * wgp, gaR);
      float vgm = aW * ewm + bW * pwm;
      float vg0 = aW * erW[tid] + bW * wpW[tid];
      float vgp = aW * ewp + bW * pwp;
      float wW = __powf(sw0 * vgm + sw1 * vg0 + sw2 * vgp, gaW);
      wbR[tid] = wR; wbW[tid] = wW;
      if (tid == 0)       { astore(hWBn + 0, wR); astore(hWBn + 2, wW); }
      if (tid == LSL - 1) { astore(hWBn + 1, wR); astore(hWBn + 3, wW); }
      float pRs = waveSum(wR), pWs = waveSum(wW);
      if (!lane) { scrC[wv] = pRs; scrD[wv] = pWs; }
    } else if (tid < LSL + CO) {
      // prefetch pacc(t+1) = bc + Wx*x(t+1) + Wo*out(t) — overlaps spin+sharpen
      const int col = tid - LSL;
      const int tt = (t + 1 < T_STEPS) ? t + 1 : T_STEPS - 1;
      float acc = bcv[col];
      const float* xr = inp + ((size_t)tt * BATCH + b) * 64;
      const float* wc = Wc + col;
#pragma unroll 8
      for (int i = 0; i < 64; ++i) acc = fmaf(xr[i], wc[(size_t)i * CO], acc);
      const float* wc2 = Wc + (size_t)64 * CO + col;
#pragma unroll 8
      for (int i = 0; i < 64; ++i) acc = fmaf(outP[i], wc2[(size_t)i * CO], acc);
      paccT[col] = acc;
    }
    __syncthreads();   // S3

    // ---------- P2b: r~ pass, l-major b128 + register reduce-scatter ----------
    {
      const int l = tid >> 1, h = tid & 1;
      const float wbl = wbR[l];
      const float4* mrow4c = (const float4*)&mem[l * MSTR + 32 * h];
      float racc[32];
#pragma unroll
      for (int q = 0; q < 8; ++q) {
        float4 v = mrow4c[q];
        racc[4 * q + 0] = wbl * v.x; racc[4 * q + 1] = wbl * v.y;
        racc[4 * q + 2] = wbl * v.z; racc[4 * q + 3] = wbl * v.w;
      }
      // 5 rounds over same-parity lanes (masks 32,16,8,4,2): lane 2p+h -> w = 32h+p
      bool u = (lane & 32) != 0; float t16[16];
#pragma unroll
      for (int j = 0; j < 16; ++j) {
        float sent = u ? racc[j] : racc[j + 16];
        float keep = u ? racc[j + 16] : racc[j];
        t16[j] = keep + __shfl_xor(sent, 32, 64);
      }
      u = (lane & 16) != 0; float t8[8];
#pragma unroll
      for (int j = 0; j < 8; ++j) {
        float sent = u ? t16[j] : t16[j + 8];
        float keep = u ? t16[j + 8] : t16[j];
        t8[j] = keep + __shfl_xor(sent, 16, 64);
      }
      u = (lane & 8) != 0; float t4[4];
#pragma unroll
      for (int j = 0; j < 4; ++j) {
        float sent = u ? t8[j] : t8[j + 4];
        float keep = u ? t8[j + 4] : t8[j];
        t4[j] = keep + __shfl_xor(sent, 8, 64);
      }
      u = (lane & 4) != 0; float t2[2];
#pragma unroll
      for (int j = 0; j < 2; ++j) {
        float sent = u ? t4[j] : t4[j + 2];
        float keep = u ? t4[j + 2] : t4[j];
        t2[j] = keep + __shfl_xor(sent, 4, 64);
      }
      u = (lane & 2) != 0;
      {
        float sent = u ? t2[0] : t2[1];
        float keep = u ? t2[1] : t2[0];
        float t1 = keep + __shfl_xor(sent, 2, 64);
        scrR[wv][32 * h + (lane >> 1)] = t1;
      }
    }
    __syncthreads();   // S4
    if (tid < 64) {
      float s = 0.f;
#pragma unroll
      for (int k = 0; k < 16; ++k) s += scrR[k][tid];
      atomicAdd(rS + tid, s);
    }
    __syncthreads();   // S5 (drain r~ adds before P flag release)
    if (tid == 0) {
      float a = 0.f, bb = 0.f;
#pragma unroll
      for (int j = 0; j < 8; ++j) { a += scrC[j]; bb += scrD[j]; }
      astoreRel(slP + 2 * g + 0, a);
      astoreRel(slP + 2 * g + 1, bb);
    }

    // ---------- P3: spin on P, normalize, stage r(t) ----------
    if (tid < LSL) {
      float pR_, pW_; spin2(slP, lane, pR_, pW_);
      invPRp = 1.f / pR_; invPWp = 1.f / pW_;
      wpR[tid] = wbR[tid] * invPRp;
      wpW[tid] = wbW[tid] * invPWp;
    }
    if (wv == 0) rstage[lane] = aload(rS + lane) * invPRp;   // r(t) for next GEMM
    __syncthreads();   // S6 (end of step)
  }
}

extern "C" void kernel_launch(void* const* d_in, const int* in_sizes, int n_in,
                              void* d_out, int out_size, void* d_ws, size_t ws_size,
                              hipStream_t stream) {
  const float* inp = (const float*)d_in[0];
  const float* Wc  = (const float*)d_in[1];
  const float* bcv = (const float*)d_in[2];
  float* dout = (float*)d_out;
  float* comm = (float*)d_ws;

  hipMemsetAsync(comm, 0, (size_t)COMM_FLOATS * sizeof(float), stream);

  void* args[] = { (void*)&inp, (void*)&Wc, (void*)&bcv, (void*)&dout, (void*)&comm };
  hipLaunchCooperativeKernel((void*)ntm_kernel, dim3(NBLK), dim3(NTHR),
                             args, 0, stream);
}

// Round 11
// 728.734 us; speedup vs baseline: 1.4015x; 1.4015x over previous
//
#include <hip/hip_runtime.h>

#define T_STEPS 32
#define BATCH   16
#define NBPB    8
#define NBLK    (BATCH * NBPB)     // 128
#define NTHR    1024
#define LSL     512                // l-slots per block
#define MSTR    68                 // 16B-aligned rows for ds_read_b128
#define NIN     192
#define CO      332

// comm floats (zeroed by hipMemsetAsync)
#define OFF_CTR   0                                        // [16][32] uints (barrier ctrs)
#define OFF_SSUM  512                                      // [b][t][4] S_R,S_W,P_R,P_W (atomicAdd)
#define OFF_RSUM  (OFF_SSUM + BATCH*T_STEPS*4)             // [b][t][64] r~ sums (atomicAdd)
#define OFF_HE    (OFF_RSUM + BATCH*T_STEPS*64)            // [b][t][g][4] er halos
#define OFF_HP    (OFF_HE + BATCH*T_STEPS*NBPB*4)          // [b][0..32][g][4] normalized wp halos
#define COMM_FLOATS (OFF_HP + BATCH*(T_STEPS+1)*NBPB*4)

__device__ __forceinline__ float waveSum(float v) {
#pragma unroll
  for (int off = 32; off > 0; off >>= 1) v += __shfl_xor(v, off, 64);
  return v;
}
__device__ __forceinline__ float sigmoidf(float x) { return 1.f / (1.f + __expf(-x)); }
__device__ __forceinline__ float softplusf(float x) { return x > 15.f ? x : log1pf(__expf(x)); }
__device__ __forceinline__ float aload(const float* p) {
  return __hip_atomic_load(p, __ATOMIC_RELAXED, __HIP_MEMORY_SCOPE_AGENT);
}
__device__ __forceinline__ void astore(float* p, float v) {
  __hip_atomic_store(p, v, __ATOMIC_RELAXED, __HIP_MEMORY_SCOPE_AGENT);
}

// r6-proven 8-block barrier: entry __syncthreads drains every thread's vmem
// (vmcnt(0) before s_barrier) so all published stores/atomics are visible
// before tid0 bumps the counter; one thread spins.
__device__ __forceinline__ void gbar(unsigned* c, unsigned expected) {
  __syncthreads();
  if (threadIdx.x == 0) {
    atomicAdd(c, 1u);
    while (__hip_atomic_load(c, __ATOMIC_RELAXED, __HIP_MEMORY_SCOPE_AGENT) < expected)
      __builtin_amdgcn_s_sleep(1);
  }
  __syncthreads();
}

__global__ void __launch_bounds__(NTHR, 1) ntm_kernel(
    const float* __restrict__ inp, const float* __restrict__ Wc,
    const float* __restrict__ bcv, float* __restrict__ dout,
    float* __restrict__ comm)
{
  const int blkid = blockIdx.x;
  const int b   = blkid & 15;     // blkid%8 == b%8 -> per-batch XCD co-location
  const int g   = blkid >> 4;
  const int tid = threadIdx.x;
  const int wv  = tid >> 6;
  const int lane = tid & 63;

  __shared__ float mem[LSL * MSTR];                 // 136 KB block-private
  __shared__ float wpR[LSL], wpW[LSL];              // normalized prev weights
  __shared__ float wbR[LSL], wbW[LSL];              // sharpened, unnormalized
  __shared__ float erR[LSL], erW[LSL];              // softmax numerators
  __shared__ __align__(16) float kr[64], kw[64];
  __shared__ __align__(16) float eldsA[2][64], aldsA[2][64];  // e/a double buffer
  __shared__ float xin[NIN], outP[64], rstage[64], psc[12];
  __shared__ float scrA[16], scrB[16], scrC[8], scrD[8];
  __shared__ float scrR[16][64];

  unsigned* ctr = (unsigned*)comm + b * 32;

  // ---------------- prologue ----------------
  for (int i = tid; i < LSL * MSTR; i += NTHR) mem[i] = 0.f;
  if (tid < LSL) { wpR[tid] = 0.f; wpW[tid] = 0.f; }
  if (g == 0 && tid == 0) { wpR[0] = 1.f; wpW[0] = 1.f; }   // w0 one-hot at l=0
  if (tid < 64) { outP[tid] = 0.f; rstage[tid] = 0.f; }
  {
    float* hp0 = comm + OFF_HP + ((size_t)(b * (T_STEPS + 1)) * NBPB + g) * 4;
    if (tid == 0) { float v = (g == 0) ? 1.f : 0.f; astore(hp0 + 0, v); astore(hp0 + 2, v); }
    if (tid == 1) { astore(hp0 + 1, 0.f); astore(hp0 + 3, 0.f); }
  }
  __syncthreads();
  unsigned expct = 0;

  for (int t = 0; t < T_STEPS; ++t) {
    float* sS  = comm + OFF_SSUM + (size_t)(b * T_STEPS + t) * 4;
    float* rS  = comm + OFF_RSUM + (size_t)(b * T_STEPS + t) * 64;
    float* hE  = comm + OFF_HE + ((size_t)(b * T_STEPS + t) * NBPB + g) * 4;
    float* hPt = comm + OFF_HP + ((size_t)(b * (T_STEPS + 1) + t) * NBPB) * 4;
    float* hPn = comm + OFF_HP + ((size_t)(b * (T_STEPS + 1) + t + 1) * NBPB + g) * 4;

    // ---------- P0: stage xin (LDS) + controller GEMM ----------
    if (tid < 64)       xin[tid] = inp[((size_t)t * BATCH + b) * 64 + tid];
    else if (tid < 128) xin[tid] = outP[tid - 64];       // out(t-1)
    else if (tid < 192) xin[tid] = rstage[tid - 128];    // r(t-1), normalized
    __syncthreads();
    if (tid < 2 * CO) {
      const int col = tid >> 1, h = tid & 1;
      float part = h ? 0.f : bcv[col];
      const float* wc = Wc + col + (size_t)(96 * h) * CO;
#pragma unroll 8
      for (int i = 0; i < 96; ++i) part = fmaf(xin[96 * h + i], wc[(size_t)i * CO], part);
      float acc = part + __shfl_xor(part, 1, 64);
      if (h == 0) {
        if (col < 64) { outP[col] = acc; if (g == 0) dout[((size_t)t * BATCH + b) * 64 + col] = acc; }
        else if (col < 128) kr[col - 64] = acc;
        else if (col < 134) psc[col - 128] = acc;          // beta_r,g_r,ga_r,s_r0..2
        else if (col < 198) kw[col - 134] = acc;
        else if (col < 204) psc[6 + col - 198] = acc;      // beta_w,g_w,ga_w,s_w0..2
        else if (col < 268) eldsA[t & 1][col - 204] = sigmoidf(acc);
        else                aldsA[t & 1][col - 268] = acc;
      }
    }
    __syncthreads();   // S1

    // per-wave redundant norms + betas (no sync needed)
    float invnkR, invnkW, betaR, betaW;
    {
      float v = kr[lane]; invnkR = 1.f / sqrtf(waveSum(v * v) + 1e-14f);
      float u = kw[lane]; invnkW = 1.f / sqrtf(waveSum(u * u) + 1e-14f);
      betaR = softplusf(psc[0]); betaW = softplusf(psc[6]);
    }

    // ---------- P1: fused lazy-update(t-1) + content addressing (b128) ----------
    {
      const int l = tid >> 1, h = tid & 1;
      float4* mrow4 = (float4*)&mem[l * MSTR + 32 * h];
      const float4* k4 = (const float4*)kr + 8 * h;
      const float4* w4 = (const float4*)kw + 8 * h;
      float ss = 0.f, dr = 0.f, dw = 0.f;
      if (t > 0) {
        const float wWl = wpW[l];                        // normalized w_W(t-1)
        const float4* e4 = (const float4*)eldsA[(t + 1) & 1] + 8 * h;
        const float4* a4 = (const float4*)aldsA[(t + 1) & 1] + 8 * h;
#pragma unroll
        for (int q = 0; q < 8; ++q) {
          float4 v = mrow4[q];
          float4 e = e4[q], a = a4[q], kk = k4[q], ww = w4[q];
          v.x = fmaf(wWl, a.x, fmaf(v.x, -(wWl * e.x), v.x));
          v.y = fmaf(wWl, a.y, fmaf(v.y, -(wWl * e.y), v.y));
          v.z = fmaf(wWl, a.z, fmaf(v.z, -(wWl * e.z), v.z));
          v.w = fmaf(wWl, a.w, fmaf(v.w, -(wWl * e.w), v.w));
          mrow4[q] = v;
          ss = fmaf(v.x, v.x, fmaf(v.y, v.y, fmaf(v.z, v.z, fmaf(v.w, v.w, ss))));
          dr = fmaf(v.x, kk.x, fmaf(v.y, kk.y, fmaf(v.z, kk.z, fmaf(v.w, kk.w, dr))));
          dw = fmaf(v.x, ww.x, fmaf(v.y, ww.y, fmaf(v.z, ww.z, fmaf(v.w, ww.w, dw))));
        }
      }
      ss += __shfl_xor(ss, 1, 64);
      dr += __shfl_xor(dr, 1, 64);
      dw += __shfl_xor(dw, 1, 64);
      float rinv = rsqrtf(ss + 1e-14f);
      float eRv = __expf(betaR * (dr * rinv * invnkR - 1.f));   // stable: K<=1
      float eWv = __expf(betaW * (dw * rinv * invnkW - 1.f));
      if (h == 0) {
        erR[l] = eRv; erW[l] = eWv;
        if (l == 0)       { astore(hE + 0, eRv); astore(hE + 2, eWv); }
        if (l == LSL - 1) { astore(hE + 1, eRv); astore(hE + 3, eWv); }
      }
      float sRl = h ? 0.f : eRv, sWl = h ? 0.f : eWv;
      sRl = waveSum(sRl); sWl = waveSum(sWl);
      if (!lane) { scrA[wv] = sRl; scrB[wv] = sWl; }
    }
    __syncthreads();   // S2
    if (tid == 0) {
      float a = 0.f, bb = 0.f;
#pragma unroll
      for (int j = 0; j < 16; ++j) { a += scrA[j]; bb += scrB[j]; }
      atomicAdd(sS + 0, a); atomicAdd(sS + 1, bb);
    }
    expct += NBPB; gbar(ctr, expct);   // barrier A

    // ---------- P2a: sharpen — R on waves 0-7, W on waves 8-15 ----------
    {
      const bool isR = (tid < LSL);
      const int l = isR ? tid : (tid - LSL);
      const float S_ = aload(sS + (isR ? 0 : 1));
      const float* er = isR ? erR : erW;
      const float* wp = isR ? wpR : wpW;
      const float gg = sigmoidf(psc[isR ? 1 : 7]);
      const float ga = softplusf(psc[isR ? 2 : 8]) + 1.f;
      const float x0 = psc[isR ? 3 : 9], x1 = psc[isR ? 4 : 10], x2 = psc[isR ? 5 : 11];
      const float mx = fmaxf(x0, fmaxf(x1, x2));
      const float e0 = __expf(x0 - mx), e1 = __expf(x1 - mx), e2 = __expf(x2 - mx);
      const float es = 1.f / (e0 + e1 + e2);
      const float s0 = e0 * es, s1 = e1 * es, s2 = e2 * es;
      const float aC = gg / S_, bC = 1.f - gg;
      const int ho = isR ? 0 : 2;   // halo offset: R uses [0,1], W uses [2,3]

      float em, pm, ep, pp;
      if (l == 0) {
        const int gm = (g + 7) & 7;
        const float* hEm = comm + OFF_HE + ((size_t)(b * T_STEPS + t) * NBPB + gm) * 4;
        em = aload(hEm + ho + 1);
        pm = aload(hPt + gm * 4 + ho + 1);
      } else { em = er[l - 1]; pm = wp[l - 1]; }
      if (l == LSL - 1) {
        const int gp = (g + 1) & 7;
        const float* hEp = comm + OFF_HE + ((size_t)(b * T_STEPS + t) * NBPB + gp) * 4;
        ep = aload(hEp + ho + 0);
        pp = aload(hPt + gp * 4 + ho + 0);
      } else { ep = er[l + 1]; pp = wp[l + 1]; }

      float wgm = aC * em + bC * pm;
      float wg0 = aC * er[l] + bC * wp[l];
      float wgp = aC * ep + bC * pp;
      float w_ = __powf(s0 * wgm + s1 * wg0 + s2 * wgp, ga);
      if (isR) wbR[l] = w_; else wbW[l] = w_;
      float ps = waveSum(w_);
      if (!lane) { if (wv < 8) scrC[wv] = ps; else scrD[wv - 8] = ps; }
    }
    __syncthreads();   // S3

    // ---------- P2b: r~ pass (l-major b128 + register reduce-scatter) ----------
    {
      const int l = tid >> 1, h = tid & 1;
      const float wbl = wbR[l];
      const float4* mrow4c = (const float4*)&mem[l * MSTR + 32 * h];
      float racc[32];
#pragma unroll
      for (int q = 0; q < 8; ++q) {
        float4 v = mrow4c[q];
        racc[4 * q + 0] = wbl * v.x; racc[4 * q + 1] = wbl * v.y;
        racc[4 * q + 2] = wbl * v.z; racc[4 * q + 3] = wbl * v.w;
      }
      bool u = (lane & 32) != 0; float t16[16];
#pragma unroll
      for (int j = 0; j < 16; ++j) {
        float sent = u ? racc[j] : racc[j + 16];
        float keep = u ? racc[j + 16] : racc[j];
        t16[j] = keep + __shfl_xor(sent, 32, 64);
      }
      u = (lane & 16) != 0; float t8[8];
#pragma unroll
      for (int j = 0; j < 8; ++j) {
        float sent = u ? t16[j] : t16[j + 8];
        float keep = u ? t16[j + 8] : t16[j];
        t8[j] = keep + __shfl_xor(sent, 16, 64);
      }
      u = (lane & 8) != 0; float t4[4];
#pragma unroll
      for (int j = 0; j < 4; ++j) {
        float sent = u ? t8[j] : t8[j + 4];
        float keep = u ? t8[j + 4] : t8[j];
        t4[j] = keep + __shfl_xor(sent, 8, 64);
      }
      u = (lane & 4) != 0; float t2[2];
#pragma unroll
      for (int j = 0; j < 2; ++j) {
        float sent = u ? t4[j] : t4[j + 2];
        float keep = u ? t4[j + 2] : t4[j];
        t2[j] = keep + __shfl_xor(sent, 4, 64);
      }
      u = (lane & 2) != 0;
      float sent = u ? t2[0] : t2[1];
      float keep = u ? t2[1] : t2[0];
      float t1 = keep + __shfl_xor(sent, 2, 64);
      scrR[wv][32 * h + (lane >> 1)] = t1;
    }
    __syncthreads();   // S4
    if (tid < 64) {
      float s = 0.f;
#pragma unroll
      for (int k = 0; k < 16; ++k) s += scrR[k][tid];
      atomicAdd(rS + tid, s);
    }
    if (tid == 0) {
      float a = 0.f, bb = 0.f;
#pragma unroll
      for (int j = 0; j < 8; ++j) { a += scrC[j]; bb += scrD[j]; }
      atomicAdd(sS + 2, a); atomicAdd(sS + 3, bb);
    }
    expct += NBPB; gbar(ctr, expct);   // barrier B

    // ---------- P3: normalize weights, publish halos, stage r(t) ----------
    {
      const float invPR = 1.f / aload(sS + 2);
      const float invPW = 1.f / aload(sS + 3);
      if (tid < LSL) {
        float nR = wbR[tid] * invPR, nW = wbW[tid] * invPW;
        wpR[tid] = nR; wpW[tid] = nW;
        if (tid == 0)       { astore(hPn + 0, nR); astore(hPn + 2, nW); }
        if (tid == LSL - 1) { astore(hPn + 1, nR); astore(hPn + 3, nW); }
      }
      if (wv == 0) rstage[lane] = aload(rS + lane) * invPR;   // r(t) for next GEMM
    }
    __syncthreads();   // S5 (end of step)
  }
}

extern "C" void kernel_launch(void* const* d_in, const int* in_sizes, int n_in,
                              void* d_out, int out_size, void* d_ws, size_t ws_size,
                              hipStream_t stream) {
  const float* inp = (const float*)d_in[0];
  const float* Wc  = (const float*)d_in[1];
  const float* bcv = (const float*)d_in[2];
  float* dout = (float*)d_out;
  float* comm = (float*)d_ws;

  hipMemsetAsync(comm, 0, (size_t)COMM_FLOATS * sizeof(float), stream);

  void* args[] = { (void*)&inp, (void*)&Wc, (void*)&bcv, (void*)&dout, (void*)&comm };
  hipLaunchCooperativeKernel((void*)ntm_kernel, dim3(NBLK), dim3(NTHR),
                             args, 0, stream);
}